// Round 12
// baseline (300.512 us; speedup 1.0000x reference)
//
#include <hip/hip_runtime.h>
#include <hip/hip_bf16.h>
#include <stdint.h>

#define BN 8192
#define DK 1024
#define BK 64
#define NT (DK / BK)          // 16 K-tiles
#define LSMOOTH 0.1f
#define EPSF 1e-7f
#define LN2F 0.69314718055994531f

typedef __bf16 bf16x8 __attribute__((ext_vector_type(8)));
typedef float f32x4 __attribute__((ext_vector_type(4)));

__device__ __forceinline__ unsigned short f2bf(float f) {
  union { float f; uint32_t u; } v; v.f = f;
  uint32_t u = v.u;
  u += 0x7fffu + ((u >> 16) & 1u);   // round-to-nearest-even
  return (unsigned short)(u >> 16);
}

// ---------------- prep: f32 -> bf16 conversion + row squared norms ----------------
__global__ __launch_bounds__(256) void prep_kernel(
    const float* __restrict__ sign, const float* __restrict__ text,
    unsigned short* __restrict__ Abf, unsigned short* __restrict__ Bbf,
    float* __restrict__ xx, float* __restrict__ yy) {
  const int b = blockIdx.x;          // 0..2*BN-1
  const int row = b & (BN - 1);
  const bool isB = b >= BN;
  const float4* src = (const float4*)((isB ? text : sign) + (size_t)row * DK);
  ushort4* dst = (ushort4*)((isB ? Bbf : Abf) + (size_t)row * DK);
  const int t = threadIdx.x;         // 256 threads, 1 float4 each (DK/4 = 256)
  float4 v = src[t];
  ushort4 o;
  o.x = f2bf(v.x); o.y = f2bf(v.y); o.z = f2bf(v.z); o.w = f2bf(v.w);
  dst[t] = o;
  float ss = v.x * v.x + v.y * v.y + v.z * v.z + v.w * v.w;
  #pragma unroll
  for (int off = 32; off; off >>= 1) ss += __shfl_down(ss, off);
  __shared__ float red[4];
  if ((t & 63) == 0) red[t >> 6] = ss;
  __syncthreads();
  if (t == 0) (isB ? yy : xx)[row] = red[0] + red[1] + red[2] + red[3];
}

// ---------------- fused GEMM: m97 clone. 128x128 tile, BK=64, single 32KB buffer ------
// 4 waves (2M x 2N), per-wave 64x64, 32 MFMA per barrier-pair. Plain full-drain loop:
// { STAGE(8 GLL); __syncthreads; 16x ds_read_b128; 32 MFMA; __syncthreads; }.
// 3 blocks/CU (launch_bounds(256,3)): co-resident blocks hide the drain stalls (m114).
// Chunk-XOR swizzle (both-sides, R8-verified 0-conflict) on 128B rows.
__global__ __launch_bounds__(256, 3) void gemm_fused(
    const unsigned short* __restrict__ Abf, const unsigned short* __restrict__ Bbf,
    const float* __restrict__ xx, const float* __restrict__ yy,
    const float* __restrict__ p_log_tau, const float* __restrict__ p_margin,
    float* __restrict__ row_partial, float* __restrict__ accums) {
  __shared__ __align__(16) char lds[32768];    // A 16KB + B 16KB

  const int tid = threadIdx.x;
  const int wave = tid >> 6, lane = tid & 63;
  const int l15 = lane & 15, g4 = lane >> 4;
  const int waveM = wave >> 1, waveN = wave & 1;        // 2 x 2
  const int bx = blockIdx.x, by = blockIdx.y;
  const int blockRow = by * 128, blockCol = bx * 128;

  // staging: per GLL call 256 threads cover 32 rows x 128B; thread t -> row t>>3,
  // 16B-chunk (t&7) ^ (row&7) (pre-swizzled source; LDS written linearly by HW)
  const int srow = tid >> 3;                            // 0..31
  const int schunk = (tid & 7) ^ (srow & 7);            // involution
  const unsigned short* aSrc = Abf + (size_t)(blockRow + srow) * DK + schunk * 8;
  const unsigned short* bSrc = Bbf + (size_t)(blockCol + srow) * DK + schunk * 8;
  const int ldst = wave * 1024;                         // wave-uniform base in 4KB call

#define GLL(gp, lp) __builtin_amdgcn_global_load_lds(                                   \
      (const __attribute__((address_space(1))) void*)(gp),                             \
      (__attribute__((address_space(3))) void*)(lp), 16, 0, 0)
#define STAGE(kt) do {                                                                  \
    _Pragma("unroll")                                                                   \
    for (int c_ = 0; c_ < 4; ++c_) {                                                    \
      GLL(aSrc + (kt) * BK + c_ * 32 * DK, lds + c_ * 4096 + ldst);                     \
      GLL(bSrc + (kt) * BK + c_ * 32 * DK, lds + 16384 + c_ * 4096 + ldst);             \
    } } while (0)
#define RD(off) (*(const bf16x8*)(lds + (off)))

  f32x4 acc[4][4];
  #pragma unroll
  for (int m = 0; m < 4; ++m)
    #pragma unroll
    for (int n = 0; n < 4; ++n)
      acc[m][n] = (f32x4){0.f, 0.f, 0.f, 0.f};

  // frag reads: row stride 128B; k-half kk -> chunks kk*4+g4, XOR row&7 (== l15&7)
  const int s7 = l15 & 7;
  const int aRow = (waveM * 64 + l15) * 128;
  const int bRow = 16384 + (waveN * 64 + l15) * 128;
  const int c0 = (g4 ^ s7) << 4;                        // kk=0 chunk byte
  const int c1 = ((4 + g4) ^ s7) << 4;                  // kk=1 chunk byte

  for (int t = 0; t < NT; ++t) {
    STAGE(t);
    __syncthreads();                                    // full drain: LDS tile ready
    bf16x8 af[4][2], bf[4][2];
    #pragma unroll
    for (int m = 0; m < 4; ++m) {
      af[m][0] = RD(aRow + m * 2048 + c0);
      af[m][1] = RD(aRow + m * 2048 + c1);
      bf[m][0] = RD(bRow + m * 2048 + c0);
      bf[m][1] = RD(bRow + m * 2048 + c1);
    }
    #pragma unroll
    for (int m = 0; m < 4; ++m)
      #pragma unroll
      for (int n = 0; n < 4; ++n) {
        acc[m][n] = __builtin_amdgcn_mfma_f32_16x16x32_bf16(af[m][0], bf[n][0], acc[m][n], 0, 0, 0);
        acc[m][n] = __builtin_amdgcn_mfma_f32_16x16x32_bf16(af[m][1], bf[n][1], acc[m][n], 0, 0, 0);
      }
    __syncthreads();                                    // reads retired before re-stage
  }
#undef STAGE
#undef GLL
#undef RD

  // ---- fused epilogue: poincare dist via log2, exp-sums, dist sums ----
  const float lt = *p_log_tau;
  const float mg = *p_margin;
  const float marg = fmaxf(mg, 0.f);
  const float tau = 1.99f / (1.f + __expf(-lt)) + 0.01f;
  const float nl = -LN2F / tau;            // exp(L2*nl) == exp(-dist/tau)
  const float em = __expf(-marg);          // diagonal exp correction factor
  const bool diagblk = (bx == by);

  float yyj[4], rcpy[4]; int gj[4];
  #pragma unroll
  for (int n = 0; n < 4; ++n) {
    gj[n] = blockCol + waveN * 64 + n * 16 + l15;        // C/D col = lane&15
    yyj[n] = yy[gj[n]];
    rcpy[n] = __builtin_amdgcn_rcpf(1.f - yyj[n]);
  }

  float dL = 0.f, dDiagL = 0.f;            // dist sums in log2 units
  float* rsum = (float*)lds;               // reuse LDS: [128 rows][2 waveN] partials

  #pragma unroll
  for (int m = 0; m < 4; ++m) {
    #pragma unroll
    for (int r = 0; r < 4; ++r) {
      const int rloc = waveM * 64 + m * 16 + g4 * 4 + r;
      const int gi = blockRow + rloc;                    // C/D row
      const float xxi = xx[gi];
      const float p2 = 2.f * __builtin_amdgcn_rcpf(1.f - xxi);
      float e_acc = 0.f;
      #pragma unroll
      for (int n = 0; n < 4; ++n) {
        const float xy = acc[m][n][r];
        const float sq = fmaxf(xxi + yyj[n] - 2.f * xy, 0.f);
        const float tt = sq * (p2 * rcpy[n]);            // arg = 1 + tt
        const float s = __builtin_amdgcn_sqrtf(tt * (tt + 2.f));
        const float w = tt + 1.f + s;                    // arg + sqrt(arg^2-1)
        const float L2 = __log2f(fmaxf(w, 1.f + EPSF));  // dist = L2 * ln2
        float e = __expf(L2 * nl);
        dL += L2;
        if (diagblk && gi == gj[n]) { dDiagL += L2; e *= em; }
        e_acc += e;
      }
      e_acc += __shfl_xor(e_acc, 1);
      e_acc += __shfl_xor(e_acc, 2);
      e_acc += __shfl_xor(e_acc, 4);
      e_acc += __shfl_xor(e_acc, 8);
      if (l15 == 0) rsum[rloc * 2 + waveN] = e_acc;
    }
  }

  // block-level scalar reductions -> 2 atomics per wave (log2 units)
  #pragma unroll
  for (int off = 32; off; off >>= 1) {
    dL += __shfl_down(dL, off);
    dDiagL += __shfl_down(dDiagL, off);
  }
  if (lane == 0) {
    atomicAdd(&accums[0], dL);
    if (diagblk) atomicAdd(&accums[1], dDiagL);
  }

  __syncthreads();
  if (tid < 128) {
    const float rs = rsum[tid * 2 + 0] + rsum[tid * 2 + 1];
    row_partial[(size_t)bx * BN + blockRow + tid] = rs;
  }
}

// ---------------- logsum: per-row sum of 64 col-tile partials, log, block-reduce ------
__global__ __launch_bounds__(256) void logsum_kernel(
    const float* __restrict__ row_partial, float* __restrict__ accums) {
  const int row = blockIdx.x * 256 + threadIdx.x;       // 32 blocks x 256 = 8192 rows
  float s = 0.f;
  #pragma unroll
  for (int c = 0; c < 64; ++c) s += row_partial[(size_t)c * BN + row];
  float lsum = __logf(s);
  #pragma unroll
  for (int off = 32; off; off >>= 1) lsum += __shfl_down(lsum, off);
  __shared__ float red[4];
  if ((threadIdx.x & 63) == 0) red[threadIdx.x >> 6] = lsum;
  __syncthreads();
  if (threadIdx.x == 0)
    atomicAdd(&accums[2], red[0] + red[1] + red[2] + red[3]);
}

// ---------------- final: linear combination ----------------
__global__ void final_kernel(
    const float* __restrict__ accums,
    const float* __restrict__ p_log_tau, const float* __restrict__ p_margin,
    float* __restrict__ out) {
  const float lt = *p_log_tau;
  const float mg = *p_margin;
  const float marg = fmaxf(mg, 0.f);
  const float tau = 1.99f / (1.f + __expf(-lt)) + 0.01f;
  const float C = marg;
  const float d_tot = accums[0] * LN2F;
  const float d_diag = accums[1] * LN2F;
  const float bf = (float)BN;
  const float mean_lse = accums[2] / bf + C;
  const float sum_scores = -d_tot / tau + marg * (bf * bf - bf);  // margin term closed-form
  const float sum_diag_scores = -d_diag / tau;
  const float loss = mean_lse
                   - (1.f - LSMOOTH) * (sum_diag_scores / bf)
                   - LSMOOTH * (sum_scores / (bf * bf));
  out[0] = loss;
  out[1] = d_diag / bf;   // pos_dist
  out[2] = tau;
  out[3] = mg;            // maximum(margin, margin) == margin
}

extern "C" void kernel_launch(void* const* d_in, const int* in_sizes, int n_in,
                              void* d_out, int out_size, void* d_ws, size_t ws_size,
                              hipStream_t stream) {
  const float* sign = (const float*)d_in[0];
  const float* text = (const float*)d_in[1];
  const float* p_log_tau = (const float*)d_in[2];
  const float* p_margin = (const float*)d_in[3];
  float* out = (float*)d_out;

  char* ws = (char*)d_ws;
  unsigned short* Abf = (unsigned short*)ws;                         // 16 MiB
  unsigned short* Bbf = (unsigned short*)(ws + (size_t)BN * DK * 2); // 16 MiB
  float* xx = (float*)(ws + (size_t)BN * DK * 4);
  float* yy = xx + BN;
  float* row_partial = yy + BN;                                      // 64 x 8192 floats
  float* accums = row_partial + 64 * BN;                             // 3 floats

  (void)hipMemsetAsync(accums, 0, 3 * sizeof(float), stream);
  prep_kernel<<<dim3(2 * BN), 256, 0, stream>>>(sign, text, Abf, Bbf, xx, yy);
  gemm_fused<<<dim3(BN / 128, BN / 128), 256, 0, stream>>>(
      Abf, Bbf, xx, yy, p_log_tau, p_margin, row_partial, accums);
  logsum_kernel<<<dim3(BN / 256), 256, 0, stream>>>(row_partial, accums);
  final_kernel<<<1, 1, 0, stream>>>(accums, p_log_tau, p_margin, out);
}